// Round 3
// baseline (244.413 us; speedup 1.0000x reference)
//
#include <hip/hip_runtime.h>

#define AOFF 10
#define NBINS 16
#define DM 256

extern "C" __global__ __launch_bounds__(256) void act_emb_kernel(
    const int* __restrict__ token_ids,
    const int* __restrict__ action_actors,
    const int* __restrict__ action_streets,
    const float* __restrict__ legal,       // [NT][16]  f32
    const float* __restrict__ actor_emb,   // [2][256]  f32
    const float* __restrict__ street_emb,  // [4][256]  f32
    const float* __restrict__ atype_emb,   // [16][256] f32
    const float* __restrict__ mlp_w,       // [16][256] f32
    const float* __restrict__ mlp_b,       // [256]     f32
    const float* __restrict__ ln_g,        // [256]     f32
    const float* __restrict__ ln_b,        // [256]     f32
    float* __restrict__ out,               // [NT][256] f32
    int n_tokens)
{
    const int lane    = threadIdx.x & 63;
    const int wave    = (int)((blockIdx.x * blockDim.x + threadIdx.x) >> 6);
    const int n_waves = (int)((gridDim.x * blockDim.x) >> 6);
    const int d0      = lane << 2;   // 4 dims per lane, 64 lanes = 256

    // ---- per-wave register-resident W fragment + b / gamma / beta ----
    float4 wf[NBINS];
    #pragma unroll
    for (int k = 0; k < NBINS; ++k)
        wf[k] = *(const float4*)(mlp_w + k * DM + d0);
    const float4 bb = *(const float4*)(mlp_b + d0);
    const float4 gg = *(const float4*)(ln_g  + d0);
    const float4 be = *(const float4*)(ln_b  + d0);

    for (int t = wave; t < n_tokens; t += n_waves) {
        float* op = out + (size_t)t * DM + d0;
        const int tok = token_ids[t];

        if (tok < AOFF || tok >= AOFF + NBINS) {   // wave-uniform branch
            *(float4*)op = make_float4(0.f, 0.f, 0.f, 0.f);
            continue;
        }

        // ---- legal masks: 64 B broadcast load ----
        const float* lg = legal + (size_t)t * NBINS;
        float4 l0 = *(const float4*)(lg + 0);
        float4 l1 = *(const float4*)(lg + 4);
        float4 l2 = *(const float4*)(lg + 8);
        float4 l3 = *(const float4*)(lg + 12);
        float lf[NBINS] = { l0.x,l0.y,l0.z,l0.w, l1.x,l1.y,l1.z,l1.w,
                            l2.x,l2.y,l2.z,l2.w, l3.x,l3.y,l3.z,l3.w };

        // ---- matvec: h = legal @ W + b  (f32 accum) ----
        float acc0 = bb.x, acc1 = bb.y, acc2 = bb.z, acc3 = bb.w;
        #pragma unroll
        for (int k = 0; k < NBINS; ++k) {
            acc0 = fmaf(lf[k], wf[k].x, acc0);
            acc1 = fmaf(lf[k], wf[k].y, acc1);
            acc2 = fmaf(lf[k], wf[k].z, acc2);
            acc3 = fmaf(lf[k], wf[k].w, acc3);
        }

        // ---- LayerNorm stats: 64-lane butterfly reduce ----
        float s  = acc0 + acc1 + acc2 + acc3;
        float q  = acc0*acc0 + acc1*acc1 + acc2*acc2 + acc3*acc3;
        #pragma unroll
        for (int off = 32; off > 0; off >>= 1) {
            s += __shfl_xor(s, off, 64);
            q += __shfl_xor(q, off, 64);
        }
        const float mu   = s * (1.0f / DM);
        const float var  = q * (1.0f / DM) - mu * mu;
        const float rstd = rsqrtf(var + 1e-5f);

        // ---- embedding gathers (L1-resident tables) ----
        const int a   = min(max(action_actors[t], 0), 1);
        const int st  = action_streets[t];
        const int aid = tok - AOFF;   // in [0,16) since masked-in
        float4 va = *(const float4*)(actor_emb  + a   * DM + d0);
        float4 vs = *(const float4*)(street_emb + st  * DM + d0);
        float4 vt = *(const float4*)(atype_emb  + aid * DM + d0);

        // ---- LN affine + ReLU + sum, store f32 ----
        float4 o;
        o.x = fmaxf((acc0 - mu) * rstd * gg.x + be.x, 0.0f) + va.x + vs.x + vt.x;
        o.y = fmaxf((acc1 - mu) * rstd * gg.y + be.y, 0.0f) + va.y + vs.y + vt.y;
        o.z = fmaxf((acc2 - mu) * rstd * gg.z + be.z, 0.0f) + va.z + vs.z + vt.z;
        o.w = fmaxf((acc3 - mu) * rstd * gg.w + be.w, 0.0f) + va.w + vs.w + vt.w;
        *(float4*)op = o;
    }
}

extern "C" void kernel_launch(void* const* d_in, const int* in_sizes, int n_in,
                              void* d_out, int out_size, void* d_ws, size_t ws_size,
                              hipStream_t stream) {
    const int* token_ids      = (const int*)d_in[0];
    const int* action_actors  = (const int*)d_in[1];
    const int* action_streets = (const int*)d_in[2];
    const float* legal      = (const float*)d_in[3];
    const float* actor_emb  = (const float*)d_in[4];
    const float* street_emb = (const float*)d_in[5];
    const float* atype_emb  = (const float*)d_in[6];
    const float* mlp_w      = (const float*)d_in[7];
    const float* mlp_b      = (const float*)d_in[8];
    const float* ln_g       = (const float*)d_in[9];
    const float* ln_b       = (const float*)d_in[10];
    float* out = (float*)d_out;

    const int n_tokens = in_sizes[0];          // B*S = 131072
    const int blocks = 1024;                   // 4096 waves, ~32 tokens/wave
    act_emb_kernel<<<blocks, 256, 0, stream>>>(
        token_ids, action_actors, action_streets, legal,
        actor_emb, street_emb, atype_emb, mlp_w, mlp_b, ln_g, ln_b,
        out, n_tokens);
}

// Round 4
// 195.357 us; speedup vs baseline: 1.2511x; 1.2511x over previous
//
#include <hip/hip_runtime.h>

#define AOFF 10
#define NBINS 16
#define DM 256
#define TPW 32          // tokens prefetched per wave batch
#define GRP 4           // tokens per ILP group

extern "C" __global__ __launch_bounds__(256) void act_emb_kernel(
    const int* __restrict__ token_ids,
    const int* __restrict__ action_actors,
    const int* __restrict__ action_streets,
    const float* __restrict__ legal,       // [NT][16]  f32
    const float* __restrict__ actor_emb,   // [2][256]  f32
    const float* __restrict__ street_emb,  // [4][256]  f32
    const float* __restrict__ atype_emb,   // [16][256] f32
    const float* __restrict__ mlp_w,       // [16][256] f32
    const float* __restrict__ mlp_b,       // [256]     f32
    const float* __restrict__ ln_g,        // [256]     f32
    const float* __restrict__ ln_b,        // [256]     f32
    float* __restrict__ out,               // [NT][256] f32
    int n_tokens)
{
    const int lane    = threadIdx.x & 63;
    const int wave    = (int)((blockIdx.x * blockDim.x + threadIdx.x) >> 6);
    const int n_waves = (int)((gridDim.x * blockDim.x) >> 6);
    const int d0      = lane << 2;   // 4 dims per lane, 64 lanes = 256

    // ---- per-wave register-resident W fragment + b / gamma / beta (L2-served, once) ----
    float4 wf[NBINS];
    #pragma unroll
    for (int k = 0; k < NBINS; ++k)
        wf[k] = *(const float4*)(mlp_w + k * DM + d0);
    const float4 bb = *(const float4*)(mlp_b + d0);
    const float4 gg = *(const float4*)(ln_g  + d0);
    const float4 be = *(const float4*)(ln_b  + d0);

    const int n_batches = (n_tokens + TPW - 1) / TPW;
    for (int b = wave; b < n_batches; b += n_waves) {
        const int base = b * TPW;

        // ---- lane-parallel id prefetch: one coalesced load per array for 32 tokens ----
        const int li  = lane & (TPW - 1);
        const int idx = min(base + li, n_tokens - 1);
        const int my_tok = token_ids[idx];
        const int my_act = action_actors[idx];
        const int my_str = action_streets[idx];

        for (int j0 = 0; j0 < TPW; j0 += GRP) {
            // ---- stage GRP tokens' legal rows: 16 independent float4 loads in flight ----
            float4 L[GRP][4];
            #pragma unroll
            for (int u = 0; u < GRP; ++u) {
                const int tt = min(base + j0 + u, n_tokens - 1);
                const float* lg = legal + (size_t)tt * NBINS;
                L[u][0] = *(const float4*)(lg + 0);
                L[u][1] = *(const float4*)(lg + 4);
                L[u][2] = *(const float4*)(lg + 8);
                L[u][3] = *(const float4*)(lg + 12);
            }

            #pragma unroll
            for (int u = 0; u < GRP; ++u) {
                const int j = j0 + u;
                const int t = base + j;
                if (t >= n_tokens) continue;                 // wave-uniform
                float* op = out + (size_t)t * DM + d0;

                const int tok = __shfl(my_tok, j, 64);
                if (tok < AOFF || tok >= AOFF + NBINS) {     // wave-uniform
                    *(float4*)op = make_float4(0.f, 0.f, 0.f, 0.f);
                    continue;
                }

                const float lf[NBINS] = {
                    L[u][0].x, L[u][0].y, L[u][0].z, L[u][0].w,
                    L[u][1].x, L[u][1].y, L[u][1].z, L[u][1].w,
                    L[u][2].x, L[u][2].y, L[u][2].z, L[u][2].w,
                    L[u][3].x, L[u][3].y, L[u][3].z, L[u][3].w };

                // ---- matvec: h = legal @ W + b ----
                float acc0 = bb.x, acc1 = bb.y, acc2 = bb.z, acc3 = bb.w;
                #pragma unroll
                for (int k = 0; k < NBINS; ++k) {
                    acc0 = fmaf(lf[k], wf[k].x, acc0);
                    acc1 = fmaf(lf[k], wf[k].y, acc1);
                    acc2 = fmaf(lf[k], wf[k].z, acc2);
                    acc3 = fmaf(lf[k], wf[k].w, acc3);
                }

                // ---- embedding gathers (issue early; L1/L2-resident tables) ----
                const int a   = min(max(__shfl(my_act, j, 64), 0), 1);
                const int st  = __shfl(my_str, j, 64);
                const int aid = tok - AOFF;
                float4 va = *(const float4*)(actor_emb  + a   * DM + d0);
                float4 vs = *(const float4*)(street_emb + st  * DM + d0);
                float4 vt = *(const float4*)(atype_emb  + aid * DM + d0);

                // ---- LayerNorm stats: 64-lane butterfly ----
                float s = acc0 + acc1 + acc2 + acc3;
                float q = acc0*acc0 + acc1*acc1 + acc2*acc2 + acc3*acc3;
                #pragma unroll
                for (int off = 32; off > 0; off >>= 1) {
                    s += __shfl_xor(s, off, 64);
                    q += __shfl_xor(q, off, 64);
                }
                const float mu   = s * (1.0f / DM);
                const float var  = q * (1.0f / DM) - mu * mu;
                const float rstd = rsqrtf(var + 1e-5f);

                float4 o;
                o.x = fmaxf((acc0 - mu) * rstd * gg.x + be.x, 0.0f) + va.x + vs.x + vt.x;
                o.y = fmaxf((acc1 - mu) * rstd * gg.y + be.y, 0.0f) + va.y + vs.y + vt.y;
                o.z = fmaxf((acc2 - mu) * rstd * gg.z + be.z, 0.0f) + va.z + vs.z + vt.z;
                o.w = fmaxf((acc3 - mu) * rstd * gg.w + be.w, 0.0f) + va.w + vs.w + vt.w;
                *(float4*)op = o;
            }
        }
    }
}

extern "C" void kernel_launch(void* const* d_in, const int* in_sizes, int n_in,
                              void* d_out, int out_size, void* d_ws, size_t ws_size,
                              hipStream_t stream) {
    const int* token_ids      = (const int*)d_in[0];
    const int* action_actors  = (const int*)d_in[1];
    const int* action_streets = (const int*)d_in[2];
    const float* legal      = (const float*)d_in[3];
    const float* actor_emb  = (const float*)d_in[4];
    const float* street_emb = (const float*)d_in[5];
    const float* atype_emb  = (const float*)d_in[6];
    const float* mlp_w      = (const float*)d_in[7];
    const float* mlp_b      = (const float*)d_in[8];
    const float* ln_g       = (const float*)d_in[9];
    const float* ln_b       = (const float*)d_in[10];
    float* out = (float*)d_out;

    const int n_tokens = in_sizes[0];   // B*S = 131072
    // 1024 blocks = 4096 waves = exactly 1 batch of 32 tokens per wave at 131072
    const int blocks = 1024;
    act_emb_kernel<<<blocks, 256, 0, stream>>>(
        token_ids, action_actors, action_streets, legal,
        actor_emb, street_emb, atype_emb, mlp_w, mlp_b, ln_g, ln_b,
        out, n_tokens);
}